// Round 16
// baseline (205.367 us; speedup 1.0000x reference)
//
#include <hip/hip_runtime.h>

#define G 64
#define C 32
#define D 18432
#define NCH 16          // chunks per group: 1024 blocks = 4/CU exact
#define TD (D / NCH)    // 1152 cols per chunk
#define NST (TD / 128)  // 9 iterations (4 waves x 32 k-cols each)
#define EPS 1e-5f
#define NS_ITERS 5

typedef __attribute__((ext_vector_type(8))) short short8v;
typedef __attribute__((ext_vector_type(4))) float float4v;

__device__ __forceinline__ void split3(float x, unsigned short& h1,
                                       unsigned short& h2, unsigned short& h3) {
    unsigned int u = __float_as_uint(x);
    unsigned int m1 = u & 0xffff0000u;
    float r1 = x - __uint_as_float(m1);
    unsigned int u2 = __float_as_uint(r1);
    unsigned int m2 = u2 & 0xffff0000u;
    float r2 = r1 - __uint_as_float(m2);
    h1 = (unsigned short)(m1 >> 16);
    h2 = (unsigned short)(m2 >> 16);
    h3 = (unsigned short)(__float_as_uint(r2) >> 16);
}

__device__ __forceinline__ void split8(const float4& v0, const float4& v1,
                                       short8v& p1, short8v& p2, short8v& p3,
                                       float& rs) {
    float x[8] = {v0.x, v0.y, v0.z, v0.w, v1.x, v1.y, v1.z, v1.w};
#pragma unroll
    for (int j = 0; j < 8; ++j) {
        unsigned short h1, h2, h3;
        rs += x[j];
        split3(x[j], h1, h2, h3);
        p1[j] = (short)h1; p2[j] = (short)h2; p3[j] = (short)h3;
    }
}

// zero the per-group arrival counters (capture-safe tiny kernel)
__global__ void k0_zero(int* __restrict__ cnt) { cnt[threadIdx.x] = 0; }

// ---------------------------------------------------------------------------
// K1: LDS-FREE partial Gram (R6/R13 core, measured-best) + "last block per
//     group" Newton-Schulz tail: the 16th block of each group to finish runs
//     the NS (identical arithmetic to the old k2) and emits MT/vv — removing
//     the separate 64-block k2 dispatch and one full-machine drain.
//     Visibility: __syncthreads (drains stores to L2) -> tid0 __threadfence
//     (agent scope: L2 writeback to IF, cross-XCD safe) -> atomicAdd;
//     reader side: atomic observation + __threadfence (invalidate) -> read.
//     grid = (NCH, G), block = 256
// ---------------------------------------------------------------------------
__global__ __launch_bounds__(256) void k1_gram(const float* __restrict__ W,
                                               float* __restrict__ psum,
                                               float* __restrict__ prow,
                                               float* __restrict__ MT,
                                               float* __restrict__ vout,
                                               int* __restrict__ cnt) {
    __shared__ float red[4 * 1056 + 4 * C];
    __shared__ float mean[C];
    __shared__ float redw[4];
    __shared__ float normsh;
    __shared__ int lastFlag;

    const int ch   = blockIdx.x;
    const int g    = blockIdx.y;
    const int bid  = g * NCH + ch;
    const int tid  = threadIdx.x;
    const int lane = tid & 63;
    const int wave = tid >> 6;

    const int rbase = lane & 15;
    const int koff  = (lane >> 4) * 8;

    const float* Zg = W + (size_t)g * C * D + (size_t)ch * TD;
    const float* p0 = Zg + (size_t)rbase * D + wave * 32 + koff;
    const float* p1 = p0 + (size_t)16 * D;

    float4v acc[2][2];
#pragma unroll
    for (int a = 0; a < 2; ++a)
#pragma unroll
        for (int b = 0; b < 2; ++b) acc[a][b] = (float4v)0.f;
    float rs0 = 0.f, rs1 = 0.f;

    float4 c00 = *(const float4*)(p0);
    float4 c01 = *(const float4*)(p0 + 4);
    float4 c10 = *(const float4*)(p1);
    float4 c11 = *(const float4*)(p1 + 4);

#pragma unroll
    for (int st = 0; st < NST; ++st) {
        float4 n00, n01, n10, n11;
        if (st + 1 < NST) {
            n00 = *(const float4*)(p0 + (st + 1) * 128);
            n01 = *(const float4*)(p0 + (st + 1) * 128 + 4);
            n10 = *(const float4*)(p1 + (st + 1) * 128);
            n11 = *(const float4*)(p1 + (st + 1) * 128 + 4);
        }
        short8v fa[3], fb[3];
        split8(c00, c01, fa[0], fa[1], fa[2], rs0);
        split8(c10, c11, fb[0], fb[1], fb[2], rs1);

        short8v* fr[2] = {fa, fb};
#pragma unroll
        for (int a = 0; a < 2; ++a)
#pragma unroll
            for (int b = 0; b < 2; ++b) {
                float4v t = acc[a][b];
                t = __builtin_amdgcn_mfma_f32_16x16x32_bf16(fr[a][0], fr[b][0], t, 0, 0, 0);
                t = __builtin_amdgcn_mfma_f32_16x16x32_bf16(fr[a][0], fr[b][1], t, 0, 0, 0);
                t = __builtin_amdgcn_mfma_f32_16x16x32_bf16(fr[a][1], fr[b][0], t, 0, 0, 0);
                t = __builtin_amdgcn_mfma_f32_16x16x32_bf16(fr[a][1], fr[b][1], t, 0, 0, 0);
                t = __builtin_amdgcn_mfma_f32_16x16x32_bf16(fr[a][0], fr[b][2], t, 0, 0, 0);
                t = __builtin_amdgcn_mfma_f32_16x16x32_bf16(fr[a][2], fr[b][0], t, 0, 0, 0);
                acc[a][b] = t;
            }
        c00 = n00; c01 = n01; c10 = n10; c11 = n11;
    }

    rs0 += __shfl_xor(rs0, 16, 64); rs0 += __shfl_xor(rs0, 32, 64);
    rs1 += __shfl_xor(rs1, 16, 64); rs1 += __shfl_xor(rs1, 32, 64);
    if (lane < 16) {
        red[4224 + wave * C + lane]      = rs0;
        red[4224 + wave * C + 16 + lane] = rs1;
    }

#pragma unroll
    for (int a = 0; a < 2; ++a)
#pragma unroll
        for (int b = 0; b < 2; ++b)
#pragma unroll
            for (int j = 0; j < 4; ++j) {
                int row = 16 * a + ((lane >> 4) << 2) + j;   // m89 C/D map
                int col = 16 * b + (lane & 15);
                red[wave * 1056 + row * 33 + col] = acc[a][b][j];
            }
    __syncthreads();

#pragma unroll
    for (int k = 0; k < 4; ++k) {
        int el = tid + 256 * k;
        int row = el >> 5, col = el & 31;
        int o = row * 33 + col;
        float sv = red[o] + red[1056 + o] + red[2112 + o] + red[3168 + o];
        psum[(size_t)bid * (C * C) + el] = sv;
    }
    if (tid < C) {
        float s = red[4224 + tid] + red[4224 + C + tid] +
                  red[4224 + 2 * C + tid] + red[4224 + 3 * C + tid];
        prow[(size_t)bid * C + tid] = s;
    }

    // ---- arrival protocol: last block of the group runs NS ----
    __syncthreads();              // drains this block's psum/prow stores (vmcnt)
    if (tid == 0) {
        __threadfence();          // release: L2 -> IF writeback (cross-XCD)
        int old = atomicAdd(&cnt[g], 1);
        lastFlag = (old == NCH - 1);
    }
    __syncthreads();
    if (!lastFlag) return;

    // ---- NS tail (identical arithmetic/order to the old k2) ----
    __threadfence();              // acquire: invalidate caches before reading
    {
        const int e   = tid & 31;
        const int cbq = tid >> 5;
        float* Sm  = red;
        float* Bm  = red + 1056;
        float* T1m = red + 2112;
        float* T2m = red + 3168;

        float selt[4];
#pragma unroll
        for (int k = 0; k < 4; ++k) {
            int el = tid + 256 * k;
            float s = 0.f;
#pragma unroll
            for (int c2 = 0; c2 < NCH; ++c2)
                s += psum[((size_t)g * NCH + c2) * (C * C) + el];
            selt[k] = s;
        }
        if (tid < C) {
            float s = 0.f;
#pragma unroll
            for (int c2 = 0; c2 < NCH; ++c2)
                s += prow[((size_t)g * NCH + c2) * C + tid];
            mean[tid] = s / (float)D;
        }
        __syncthreads();

        float ss = 0.f;
#pragma unroll
        for (int k = 0; k < 4; ++k) {
            int el = tid + 256 * k;
            int c = el >> 5;
            float sv = selt[k] - (float)D * mean[c] * mean[e];
            if (c == e) sv += EPS;
            Sm[c * 33 + e] = sv;
            ss = fmaf(sv, sv, ss);
        }
#pragma unroll
        for (int off = 32; off >= 1; off >>= 1) ss += __shfl_xor(ss, off, 64);
        if ((tid & 63) == 0) redw[tid >> 6] = ss;
        __syncthreads();
        if (tid == 0) normsh = sqrtf(redw[0] + redw[1] + redw[2] + redw[3]);
        __syncthreads();
        const float inv_norm = 1.0f / normsh;
#pragma unroll
        for (int k = 0; k < 4; ++k) {
            int c = cbq + 8 * k;
            Sm[c * 33 + e] *= inv_norm;
            Bm[c * 33 + e] = (c == e) ? 1.f : 0.f;
        }
        __syncthreads();

        for (int it = 0; it < NS_ITERS; ++it) {
#pragma unroll
            for (int k = 0; k < 4; ++k) {
                int c = cbq + 8 * k;
                float s = 0.f;
                for (int kk = 0; kk < C; ++kk)
                    s = fmaf(Bm[c * 33 + kk], Bm[kk * 33 + e], s);
                T1m[c * 33 + e] = s;
            }
            __syncthreads();
#pragma unroll
            for (int k = 0; k < 4; ++k) {
                int c = cbq + 8 * k;
                float s = 0.f;
                for (int kk = 0; kk < C; ++kk)
                    s = fmaf(T1m[c * 33 + kk], Bm[kk * 33 + e], s);
                T2m[c * 33 + e] = s;
            }
            __syncthreads();
            float pv[4];
#pragma unroll
            for (int k = 0; k < 4; ++k) {
                int c = cbq + 8 * k;
                float s = 0.f;
                for (int kk = 0; kk < C; ++kk)
                    s = fmaf(T2m[c * 33 + kk], Sm[kk * 33 + e], s);
                pv[k] = s;
            }
#pragma unroll
            for (int k = 0; k < 4; ++k) {
                int c = cbq + 8 * k;
                Bm[c * 33 + e] = 1.5f * Bm[c * 33 + e] - 0.5f * pv[k];
            }
            __syncthreads();
        }

        const float invs = 1.0f / sqrtf(normsh);
#pragma unroll
        for (int k = 0; k < 4; ++k) {
            int c = cbq + 8 * k;
            MT[(size_t)g * (C * C) + e * C + c] = Bm[c * 33 + e] * invs;
        }
        if (tid < C) {
            float s = 0.f;
            for (int ee = 0; ee < C; ++ee)
                s = fmaf(Bm[tid * 33 + ee] * invs, mean[ee], s);
            vout[(size_t)g * C + tid] = s;
        }
    }
}

// ---------------------------------------------------------------------------
// K3: W_out = M * Z - v * 1^T  (float2/lane, s_load M path, nt stores).
//     R15 form verbatim (measured-best).
// ---------------------------------------------------------------------------
__global__ __launch_bounds__(256) void k3_apply(const float* __restrict__ W,
                                                const float* __restrict__ MT,
                                                const float* __restrict__ vv,
                                                float* __restrict__ out) {
    const int blocksPerGroup = D / 512;     // 36
    const int g   = blockIdx.x / blocksPerGroup;
    const int cbk = blockIdx.x % blocksPerGroup;
    const int d0  = cbk * 512 + (int)threadIdx.x * 2;
    const float* Zg = W + (size_t)g * C * D + d0;
    const float* Mg = MT + (size_t)g * (C * C);

    float accx[C], accy[C];
#pragma unroll
    for (int r = 0; r < C; ++r) { accx[r] = 0.f; accy[r] = 0.f; }

    for (int e = 0; e < C; ++e) {
        float2 z = *(const float2*)(Zg + (size_t)e * D);
#pragma unroll
        for (int r = 0; r < C; ++r) {
            float m = Mg[e * C + r];   // wave-uniform -> s_load (scalar pipe)
            accx[r] = fmaf(m, z.x, accx[r]);
            accy[r] = fmaf(m, z.y, accy[r]);
        }
    }

    float* Og = out + (size_t)g * C * D + d0;
#pragma unroll
    for (int r = 0; r < C; ++r) {
        float vr = vv[g * C + r];      // wave-uniform
        float2 o = make_float2(accx[r] - vr, accy[r] - vr);
        double dv;
        __builtin_memcpy(&dv, &o, 8);
        __builtin_nontemporal_store(dv, (double*)(Og + (size_t)r * D));
    }
}

extern "C" void kernel_launch(void* const* d_in, const int* in_sizes, int n_in,
                              void* d_out, int out_size, void* d_ws, size_t ws_size,
                              hipStream_t stream) {
    const float* w = (const float*)d_in[0];
    float* out = (float*)d_out;

    float* psum = (float*)d_ws;                          // G*NCH*1024 floats (4.2 MB)
    float* prow = psum + (size_t)(G * NCH) * (C * C);    // G*NCH*32
    float* MT   = prow + (size_t)(G * NCH) * C;          // G*1024
    float* vv   = MT   + (size_t)G * (C * C);            // G*32
    int*   cnt  = (int*)(vv + (size_t)G * C);            // G ints

    k0_zero <<<1, G, 0, stream>>>(cnt);
    k1_gram <<<dim3(NCH, G), 256, 0, stream>>>(w, psum, prow, MT, vv, cnt);
    k3_apply<<<G * (D / 512), 256, 0, stream>>>(w, MT, vv, out);
}

// Round 17
// 92.017 us; speedup vs baseline: 2.2318x; 2.2318x over previous
//
#include <hip/hip_runtime.h>

#define G 64
#define C 32
#define D 18432
#define NCH 16          // chunks per group: 1024 blocks = 4/CU exact
#define TD (D / NCH)    // 1152 cols per chunk
#define NST (TD / 128)  // 9 iterations (4 waves x 32 k-cols each)
#define EPS 1e-5f
#define NS_ITERS 5

typedef __attribute__((ext_vector_type(8))) short short8v;
typedef __attribute__((ext_vector_type(4))) float float4v;

__device__ __forceinline__ void split3(float x, unsigned short& h1,
                                       unsigned short& h2, unsigned short& h3) {
    unsigned int u = __float_as_uint(x);
    unsigned int m1 = u & 0xffff0000u;
    float r1 = x - __uint_as_float(m1);
    unsigned int u2 = __float_as_uint(r1);
    unsigned int m2 = u2 & 0xffff0000u;
    float r2 = r1 - __uint_as_float(m2);
    h1 = (unsigned short)(m1 >> 16);
    h2 = (unsigned short)(m2 >> 16);
    h3 = (unsigned short)(__float_as_uint(r2) >> 16);
}

// split 8 fp32 (two float4) into three bf16x8 fragments, accumulate row sum
__device__ __forceinline__ void split8(const float4& v0, const float4& v1,
                                       short8v& p1, short8v& p2, short8v& p3,
                                       float& rs) {
    float x[8] = {v0.x, v0.y, v0.z, v0.w, v1.x, v1.y, v1.z, v1.w};
#pragma unroll
    for (int j = 0; j < 8; ++j) {
        unsigned short h1, h2, h3;
        rs += x[j];
        split3(x[j], h1, h2, h3);
        p1[j] = (short)h1; p2[j] = (short)h2; p3[j] = (short)h3;
    }
}

// ---------------------------------------------------------------------------
// K1: LDS-FREE partial Gram P = Z_chunk * Z_chunk^T via bf16 MFMA (3-term
//     split, fp32-grade). Lane l's MFMA fragment (rows l&15 / +16, k-slice
//     (l>>4)*8) IS a coalesced global load -> no LDS staging, no barriers in
//     the K-loop; loads pipeline freely across iterations via vmcnt.
//     grid = (NCH, G), block = 256 (4 waves, each owns 32 k-cols per iter)
// ---------------------------------------------------------------------------
__global__ __launch_bounds__(256) void k1_gram(const float* __restrict__ W,
                                               float* __restrict__ psum,
                                               float* __restrict__ prow) {
    __shared__ float red[4 * 1056 + 4 * C];

    const int ch   = blockIdx.x;
    const int g    = blockIdx.y;
    const int bid  = g * NCH + ch;
    const int tid  = threadIdx.x;
    const int lane = tid & 63;
    const int wave = tid >> 6;

    const int rbase = lane & 15;
    const int koff  = (lane >> 4) * 8;

    const float* Zg = W + (size_t)g * C * D + (size_t)ch * TD;
    const float* p0 = Zg + (size_t)rbase * D + wave * 32 + koff;
    const float* p1 = p0 + (size_t)16 * D;

    float4v acc[2][2];
#pragma unroll
    for (int a = 0; a < 2; ++a)
#pragma unroll
        for (int b = 0; b < 2; ++b) acc[a][b] = (float4v)0.f;
    float rs0 = 0.f, rs1 = 0.f;

    float4 c00 = *(const float4*)(p0);
    float4 c01 = *(const float4*)(p0 + 4);
    float4 c10 = *(const float4*)(p1);
    float4 c11 = *(const float4*)(p1 + 4);

#pragma unroll
    for (int st = 0; st < NST; ++st) {
        float4 n00, n01, n10, n11;
        if (st + 1 < NST) {
            n00 = *(const float4*)(p0 + (st + 1) * 128);
            n01 = *(const float4*)(p0 + (st + 1) * 128 + 4);
            n10 = *(const float4*)(p1 + (st + 1) * 128);
            n11 = *(const float4*)(p1 + (st + 1) * 128 + 4);
        }
        short8v fa[3], fb[3];
        split8(c00, c01, fa[0], fa[1], fa[2], rs0);
        split8(c10, c11, fb[0], fb[1], fb[2], rs1);

        short8v* fr[2] = {fa, fb};
#pragma unroll
        for (int a = 0; a < 2; ++a)
#pragma unroll
            for (int b = 0; b < 2; ++b) {
                float4v t = acc[a][b];
                t = __builtin_amdgcn_mfma_f32_16x16x32_bf16(fr[a][0], fr[b][0], t, 0, 0, 0);
                t = __builtin_amdgcn_mfma_f32_16x16x32_bf16(fr[a][0], fr[b][1], t, 0, 0, 0);
                t = __builtin_amdgcn_mfma_f32_16x16x32_bf16(fr[a][1], fr[b][0], t, 0, 0, 0);
                t = __builtin_amdgcn_mfma_f32_16x16x32_bf16(fr[a][1], fr[b][1], t, 0, 0, 0);
                t = __builtin_amdgcn_mfma_f32_16x16x32_bf16(fr[a][0], fr[b][2], t, 0, 0, 0);
                t = __builtin_amdgcn_mfma_f32_16x16x32_bf16(fr[a][2], fr[b][0], t, 0, 0, 0);
                acc[a][b] = t;
            }
        c00 = n00; c01 = n01; c10 = n10; c11 = n11;
    }

    rs0 += __shfl_xor(rs0, 16, 64); rs0 += __shfl_xor(rs0, 32, 64);
    rs1 += __shfl_xor(rs1, 16, 64); rs1 += __shfl_xor(rs1, 32, 64);
    if (lane < 16) {
        red[4224 + wave * C + lane]      = rs0;
        red[4224 + wave * C + 16 + lane] = rs1;
    }

#pragma unroll
    for (int a = 0; a < 2; ++a)
#pragma unroll
        for (int b = 0; b < 2; ++b)
#pragma unroll
            for (int j = 0; j < 4; ++j) {
                int row = 16 * a + ((lane >> 4) << 2) + j;   // m89 C/D map
                int col = 16 * b + (lane & 15);
                red[wave * 1056 + row * 33 + col] = acc[a][b][j];
            }
    __syncthreads();

#pragma unroll
    for (int k = 0; k < 4; ++k) {
        int el = tid + 256 * k;
        int row = el >> 5, col = el & 31;
        int o = row * 33 + col;
        float sv = red[o] + red[1056 + o] + red[2112 + o] + red[3168 + o];
        psum[(size_t)bid * (C * C) + el] = sv;
    }
    if (tid < C) {
        float s = red[4224 + tid] + red[4224 + C + tid] +
                  red[4224 + 2 * C + tid] + red[4224 + 3 * C + tid];
        prow[(size_t)bid * C + tid] = s;
    }
}

// ---------------------------------------------------------------------------
// K2: per group: S = sum(partials) - D*m*m^T + EPS*I; Frobenius-normalize;
//     5 Newton-Schulz iterations; emit M^T and v = M*m.  (compile-time NCH)
// ---------------------------------------------------------------------------
__global__ __launch_bounds__(256) void k2_ns(const float* __restrict__ psum,
                                             const float* __restrict__ prow,
                                             float* __restrict__ MT,
                                             float* __restrict__ vout) {
    __shared__ float S[C][C + 1];
    __shared__ float B[C][C + 1];
    __shared__ float T1[C][C + 1];
    __shared__ float T2[C][C + 1];
    __shared__ float mean[C];
    __shared__ float redw[4];
    __shared__ float normsh;

    const int g   = blockIdx.x;
    const int tid = threadIdx.x;
    const int e   = tid & 31;
    const int cbq = tid >> 5;

    float selt[4];
#pragma unroll
    for (int k = 0; k < 4; ++k) {
        int el = tid + 256 * k;
        float s = 0.f;
#pragma unroll
        for (int ch = 0; ch < NCH; ++ch)
            s += psum[((size_t)g * NCH + ch) * (C * C) + el];
        selt[k] = s;
    }
    if (tid < C) {
        float s = 0.f;
#pragma unroll
        for (int ch = 0; ch < NCH; ++ch)
            s += prow[((size_t)g * NCH + ch) * C + tid];
        mean[tid] = s / (float)D;
    }
    __syncthreads();

    float ss = 0.f;
#pragma unroll
    for (int k = 0; k < 4; ++k) {
        int el = tid + 256 * k;
        int c = el >> 5;
        float sv = selt[k] - (float)D * mean[c] * mean[e];
        if (c == e) sv += EPS;
        S[c][e] = sv;
        ss = fmaf(sv, sv, ss);
    }
#pragma unroll
    for (int off = 32; off >= 1; off >>= 1) ss += __shfl_xor(ss, off, 64);
    if ((tid & 63) == 0) redw[tid >> 6] = ss;
    __syncthreads();
    if (tid == 0) normsh = sqrtf(redw[0] + redw[1] + redw[2] + redw[3]);
    __syncthreads();
    const float inv_norm = 1.0f / normsh;
#pragma unroll
    for (int k = 0; k < 4; ++k) {
        int c = cbq + 8 * k;
        S[c][e] *= inv_norm;
        B[c][e] = (c == e) ? 1.f : 0.f;
    }
    __syncthreads();

    for (int it = 0; it < NS_ITERS; ++it) {
#pragma unroll
        for (int k = 0; k < 4; ++k) {
            int c = cbq + 8 * k;
            float s = 0.f;
            for (int kk = 0; kk < C; ++kk)
                s = fmaf(B[c][kk], B[kk][e], s);
            T1[c][e] = s;
        }
        __syncthreads();
#pragma unroll
        for (int k = 0; k < 4; ++k) {
            int c = cbq + 8 * k;
            float s = 0.f;
            for (int kk = 0; kk < C; ++kk)
                s = fmaf(T1[c][kk], B[kk][e], s);
            T2[c][e] = s;
        }
        __syncthreads();
        float pv[4];
#pragma unroll
        for (int k = 0; k < 4; ++k) {
            int c = cbq + 8 * k;
            float s = 0.f;
            for (int kk = 0; kk < C; ++kk)
                s = fmaf(T2[c][kk], S[kk][e], s);
            pv[k] = s;
        }
#pragma unroll
        for (int k = 0; k < 4; ++k) {
            int c = cbq + 8 * k;
            B[c][e] = 1.5f * B[c][e] - 0.5f * pv[k];
        }
        __syncthreads();
    }

    const float invs = 1.0f / sqrtf(normsh);
#pragma unroll
    for (int k = 0; k < 4; ++k) {
        int c = cbq + 8 * k;
        MT[(size_t)g * (C * C) + e * C + c] = B[c][e] * invs;
    }
    if (tid < C) {
        float s = 0.f;
        for (int ee = 0; ee < C; ++ee)
            s = fmaf(B[tid][ee] * invs, mean[ee], s);
        vout[(size_t)g * C + tid] = s;
    }
}

// ---------------------------------------------------------------------------
// K3: W_out = M * Z - v * 1^T   (per group), 2 cols per thread (float2).
//     Non-temporal stores for `out` (never re-read) keep W L3-resident.
// ---------------------------------------------------------------------------
__global__ __launch_bounds__(256) void k3_apply(const float* __restrict__ W,
                                                const float* __restrict__ MT,
                                                const float* __restrict__ vv,
                                                float* __restrict__ out) {
    const int blocksPerGroup = D / 512;     // 36
    const int g   = blockIdx.x / blocksPerGroup;
    const int cbk = blockIdx.x % blocksPerGroup;
    const int d0  = cbk * 512 + (int)threadIdx.x * 2;
    const float* Zg = W + (size_t)g * C * D + d0;
    const float* Mg = MT + (size_t)g * (C * C);

    float accx[C], accy[C];
#pragma unroll
    for (int r = 0; r < C; ++r) { accx[r] = 0.f; accy[r] = 0.f; }

    for (int e = 0; e < C; ++e) {
        float2 z = *(const float2*)(Zg + (size_t)e * D);
#pragma unroll
        for (int r = 0; r < C; ++r) {
            float m = Mg[e * C + r];   // wave-uniform -> s_load (scalar pipe)
            accx[r] = fmaf(m, z.x, accx[r]);
            accy[r] = fmaf(m, z.y, accy[r]);
        }
    }

    float* Og = out + (size_t)g * C * D + d0;
#pragma unroll
    for (int r = 0; r < C; ++r) {
        float vr = vv[g * C + r];      // wave-uniform
        float2 o = make_float2(accx[r] - vr, accy[r] - vr);
        double dv;
        __builtin_memcpy(&dv, &o, 8);
        __builtin_nontemporal_store(dv, (double*)(Og + (size_t)r * D));
    }
}

extern "C" void kernel_launch(void* const* d_in, const int* in_sizes, int n_in,
                              void* d_out, int out_size, void* d_ws, size_t ws_size,
                              hipStream_t stream) {
    const float* w = (const float*)d_in[0];
    float* out = (float*)d_out;

    float* psum = (float*)d_ws;                          // G*NCH*1024 floats (4.2 MB)
    float* prow = psum + (size_t)(G * NCH) * (C * C);    // G*NCH*32
    float* MT   = prow + (size_t)(G * NCH) * C;          // G*1024
    float* vv   = MT   + (size_t)G * (C * C);            // G*32

    k1_gram <<<dim3(NCH, G), 256, 0, stream>>>(w, psum, prow);
    k2_ns   <<<G,            256, 0, stream>>>(psum, prow, MT, vv);
    k3_apply<<<G * (D / 512), 256, 0, stream>>>(w, MT, vv, out);
}